// Round 4
// baseline (1465.238 us; speedup 1.0000x reference)
//
#include <hip/hip_runtime.h>

#define BATCH 2048
#define CH 512            // conv batch-chunk size (4 chunks)

// ---------------------------------------------------------------------------
// Conv1: state [B,84,84,3] NHWC fp32 -> a1c [CH,32,20,20] NCHW fp32, 8x8 s4
// grid (CH, 5): (chunk image, group of 4 output rows)
// ---------------------------------------------------------------------------
__global__ __launch_bounds__(256) void conv1_kernel(
    const float* __restrict__ state, const float* __restrict__ k1,
    const float* __restrict__ c1, float* __restrict__ a1c, int b0)
{
  __shared__ __align__(16) float wl2[192 * 36];   // row = c*64+ky*8+kx, col = oc
  __shared__ __align__(16) float il[3 * 20 * 84]; // planar [c][y][x]
  const int bl  = blockIdx.x;
  const int b   = b0 + bl;
  const int oy0 = blockIdx.y * 4;
  const int t   = threadIdx.x;

  for (int i = t; i < 6144; i += 256) {
    int oc = i / 192, row = i % 192;
    wl2[row * 36 + oc] = k1[oc * 192 + row];
  }
  const float* sp = state + (size_t)b * (84 * 84 * 3) + (size_t)(oy0 * 4) * (84 * 3);
  for (int i = t; i < 20 * 84 * 3; i += 256) {
    int c = i % 3, x = (i / 3) % 84, y = i / 252;
    il[(c * 20 + y) * 84 + x] = sp[i];
  }
  __syncthreads();

  const int ocg = (t & 7) * 4;
  const int oyl = (t >> 3) & 3;
  const int oxg = t >> 5;
  const int nox = (oxg < 4) ? 3 : 2;

  float acc[4][3] = {};
  for (int c = 0; c < 3; ++c) {
    for (int ky = 0; ky < 8; ++ky) {
      const float* irow = &il[(c * 20 + oyl * 4 + ky) * 84];
      float x[3][8];
      #pragma unroll
      for (int j = 0; j < 3; ++j) {
        if (j < nox) {
          const float4* ip = (const float4*)&irow[(oxg + j * 8) * 4];
          float4 x0 = ip[0], x1 = ip[1];
          x[j][0] = x0.x; x[j][1] = x0.y; x[j][2] = x0.z; x[j][3] = x0.w;
          x[j][4] = x1.x; x[j][5] = x1.y; x[j][6] = x1.z; x[j][7] = x1.w;
        }
      }
      #pragma unroll
      for (int kx = 0; kx < 8; ++kx) {
        const float4 wv = *(const float4*)&wl2[(c * 64 + ky * 8 + kx) * 36 + ocg];
        const float wa[4] = {wv.x, wv.y, wv.z, wv.w};
        #pragma unroll
        for (int j = 0; j < 3; ++j)
          if (j < nox)
            #pragma unroll
            for (int i = 0; i < 4; ++i)
              acc[i][j] += x[j][kx] * wa[i];
      }
    }
  }

  float* op = a1c + (size_t)bl * (32 * 400);
  for (int i = 0; i < 4; ++i) {
    float bias = c1[ocg + i];
    for (int j = 0; j < nox; ++j) {
      int ox = oxg + j * 8;
      op[((ocg + i) * 20 + (oy0 + oyl)) * 20 + ox] = fmaxf(acc[i][j] + bias, 0.f);
    }
  }
}

// ---------------------------------------------------------------------------
// Conv2: a1c [CH,32,20,20] -> a2c [CH,64,9,9], k 4x4 s2, relu.
// ---------------------------------------------------------------------------
__global__ __launch_bounds__(256) void conv2_kernel(
    const float* __restrict__ a1c, const float* __restrict__ k2,
    const float* __restrict__ c2, float* __restrict__ a2c)
{
  __shared__ __align__(16) float wl2[128 * 68];  // row = cc*16+ky*4+kx
  __shared__ __align__(16) float il[8 * 400];    // [cc][20][20]
  const int bl = blockIdx.x;
  const int t  = threadIdx.x;
  const int oc0  = (t & 15) * 4;
  const int pixg = t >> 4;

  float acc[4][6] = {};
  for (int cb = 0; cb < 32; cb += 8) {
    __syncthreads();
    for (int i = t; i < 8192; i += 256) {
      int oc = i >> 7, r = i & 127;
      wl2[r * 68 + oc] = k2[oc * 512 + cb * 16 + r];
    }
    const float* ap = a1c + (size_t)bl * (32 * 400) + cb * 400;
    for (int i = t; i < 3200; i += 256) il[i] = ap[i];
    __syncthreads();

    for (int cc = 0; cc < 8; ++cc) {
      for (int ky = 0; ky < 4; ++ky) {
        float x[6][4];
        #pragma unroll
        for (int j = 0; j < 6; ++j) {
          int p = pixg + j * 16;
          if (p < 81) {
            int oyy = p / 9, oxx = p - oyy * 9;
            const float2* xp = (const float2*)&il[(cc * 20 + oyy * 2 + ky) * 20 + oxx * 2];
            float2 xa = xp[0], xb = xp[1];
            x[j][0] = xa.x; x[j][1] = xa.y; x[j][2] = xb.x; x[j][3] = xb.y;
          }
        }
        #pragma unroll
        for (int kx = 0; kx < 4; ++kx) {
          const float4 wv = *(const float4*)&wl2[(cc * 16 + ky * 4 + kx) * 68 + oc0];
          const float wa[4] = {wv.x, wv.y, wv.z, wv.w};
          #pragma unroll
          for (int j = 0; j < 6; ++j)
            if (pixg + j * 16 < 81)
              #pragma unroll
              for (int i = 0; i < 4; ++i)
                acc[i][j] += x[j][kx] * wa[i];
        }
      }
    }
  }

  float* op = a2c + (size_t)bl * (64 * 81);
  for (int i = 0; i < 4; ++i) {
    float bias = c2[oc0 + i];
    for (int j = 0; j < 6; ++j) {
      int p = pixg + j * 16;
      if (p < 81) op[(oc0 + i) * 81 + p] = fmaxf(acc[i][j] + bias, 0.f);
    }
  }
}

// ---------------------------------------------------------------------------
// Conv3: a2c [CH,64,9,9] -> a3 [B,3136] (NCHW flat), k 3x3 s1, relu.
// ---------------------------------------------------------------------------
__global__ __launch_bounds__(256) void conv3_kernel(
    const float* __restrict__ a2c, const float* __restrict__ k3,
    const float* __restrict__ c3, float* __restrict__ a3, int b0)
{
  __shared__ __align__(16) float wl2[72 * 68];   // row = cc*9+ky*3+kx
  __shared__ __align__(16) float il[8 * 9 * 12]; // [cc][9][x pad12]
  const int bl = blockIdx.x;
  const int t  = threadIdx.x;
  const int oc0  = (t & 15) * 4;
  const int pixg = t >> 4;

  float acc[4][4] = {};
  for (int cb = 0; cb < 64; cb += 8) {
    __syncthreads();
    for (int i = t; i < 4608; i += 256) {
      int oc = i / 72, row = i % 72;
      wl2[row * 68 + oc] = k3[oc * 576 + cb * 9 + row];
    }
    const float* ap = a2c + (size_t)bl * (64 * 81) + cb * 81;
    for (int i = t; i < 648; i += 256) {
      int cc = i / 81, r = i % 81, y = r / 9, xx = r - y * 9;
      il[(cc * 9 + y) * 12 + xx] = ap[i];
    }
    __syncthreads();

    for (int cc = 0; cc < 8; ++cc) {
      for (int ky = 0; ky < 3; ++ky) {
        float x[4][3];
        #pragma unroll
        for (int j = 0; j < 4; ++j) {
          int p = pixg + j * 16;
          if (p < 49) {
            int oyy = p / 7, oxx = p - oyy * 7;
            const float* ir = &il[(cc * 9 + oyy + ky) * 12 + oxx];
            x[j][0] = ir[0]; x[j][1] = ir[1]; x[j][2] = ir[2];
          }
        }
        #pragma unroll
        for (int kx = 0; kx < 3; ++kx) {
          const float4 wv = *(const float4*)&wl2[(cc * 9 + ky * 3 + kx) * 68 + oc0];
          const float wa[4] = {wv.x, wv.y, wv.z, wv.w};
          #pragma unroll
          for (int j = 0; j < 4; ++j)
            if (pixg + j * 16 < 49)
              #pragma unroll
              for (int i = 0; i < 4; ++i)
                acc[i][j] += x[j][kx] * wa[i];
        }
      }
    }
  }

  float* op = a3 + (size_t)(b0 + bl) * 3136;
  for (int i = 0; i < 4; ++i) {
    float bias = c3[oc0 + i];
    for (int j = 0; j < 4; ++j) {
      int p = pixg + j * 16;
      if (p < 49) op[(oc0 + i) * 49 + p] = fmaxf(acc[i][j] + bias, 0.f);
    }
  }
}

// ---------------------------------------------------------------------------
// Normalize rm_state to int32 (auto-detect int32 vs int64 storage).
// ---------------------------------------------------------------------------
__global__ void rm_norm_kernel(const void* __restrict__ rmv, int* __restrict__ rm32)
{
  __shared__ int isI32;
  const int t = threadIdx.x;
  if (t == 0) isI32 = 0;
  __syncthreads();
  unsigned long long v = ((const unsigned long long*)rmv)[t]; // first 8KB, safe either way
  if (v >= 8ull) isI32 = 1;
  __syncthreads();
  const int i32 = isI32;
  for (int b = t; b < BATCH; b += 1024)
    rm32[b] = i32 ? ((const int*)rmv)[b] : (int)((const long long*)rmv)[b];
}

// ---------------------------------------------------------------------------
// GEMM1 (all experts): H1a[e][s][64] += a3[s][k]*W1[e][k][64] over K-slice 448.
// grid (8, 32, 7); fp32 atomic accumulation.
// ---------------------------------------------------------------------------
__global__ __launch_bounds__(256) void gemm1_all_kernel(
    const float* __restrict__ a3, const float* __restrict__ W1,
    float* __restrict__ H1a)
{
  __shared__ __align__(16) float At[32 * 68]; // [kk][r pad68]
  __shared__ __align__(16) float Bw[32 * 64]; // [kk][h]
  const int e  = blockIdx.x;
  const int s0 = blockIdx.y * 64;
  const int ks = blockIdx.z;
  const int t  = threadIdx.x;

  const int tx = t & 15, ty = t >> 4;
  const int c0 = tx * 4, r0 = ty * 4;
  const float* W1e = W1 + (size_t)e * 3136 * 64;
  float acc[4][4] = {};
  const int kbase = ks * 448;

  for (int k0 = kbase; k0 < kbase + 448; k0 += 32) {
    __syncthreads();
    {
      int i = t;
      #pragma unroll
      for (int pass = 0; pass < 2; ++pass, i += 256) {
        int r = i >> 3, k4 = (i & 7) * 4;
        float4 v = *(const float4*)(a3 + (size_t)(s0 + r) * 3136 + k0 + k4);
        At[(k4 + 0) * 68 + r] = v.x; At[(k4 + 1) * 68 + r] = v.y;
        At[(k4 + 2) * 68 + r] = v.z; At[(k4 + 3) * 68 + r] = v.w;
      }
      int i2 = t;
      #pragma unroll
      for (int pass = 0; pass < 2; ++pass, i2 += 256) {
        int kk = i2 >> 4, h4 = (i2 & 15) * 4;
        *(float4*)&Bw[kk * 64 + h4] = *(const float4*)&W1e[(size_t)(k0 + kk) * 64 + h4];
      }
    }
    __syncthreads();
    #pragma unroll
    for (int kk = 0; kk < 32; ++kk) {
      float4 a = *(const float4*)&At[kk * 68 + r0];
      float4 bb = *(const float4*)&Bw[kk * 64 + c0];
      float av[4] = {a.x, a.y, a.z, a.w}, bv[4] = {bb.x, bb.y, bb.z, bb.w};
      #pragma unroll
      for (int ii = 0; ii < 4; ++ii)
        #pragma unroll
        for (int j = 0; j < 4; ++j)
          acc[ii][j] += av[ii] * bv[j];
    }
  }

  float* Hdst = H1a + (size_t)e * (BATCH * 64);
  #pragma unroll
  for (int ii = 0; ii < 4; ++ii)
    #pragma unroll
    for (int j = 0; j < 4; ++j)
      atomicAdd(&Hdst[(size_t)(s0 + r0 + ii) * 64 + c0 + j], acc[ii][j]);
}

// ---------------------------------------------------------------------------
// MLP tail (all experts): bias+relu H1a, layers 2..5, layer 6; write out[s]
// only where rm32[s]==e. grid (8, 32).
// BUGFIX r4: W6l has 384 entries but blockDim is 256 — stage with a strided
// loop, not `if (t < 384)` (left W6l[256..383] = stale LDS -> deterministic
// corruption of final-layer terms k>=43; the sole cause of r1/r2's 8.44e-3).
// ---------------------------------------------------------------------------
__global__ __launch_bounds__(256) void tail_all_kernel(
    const float* __restrict__ H1a, const int* __restrict__ rm32,
    const float* __restrict__ B1,
    const float* __restrict__ W2, const float* __restrict__ B2,
    const float* __restrict__ W3, const float* __restrict__ B3,
    const float* __restrict__ W4, const float* __restrict__ B4,
    const float* __restrict__ W5, const float* __restrict__ B5,
    const float* __restrict__ W6, const float* __restrict__ B6,
    float* __restrict__ out)
{
  __shared__ __align__(16) float Wl[4096];
  __shared__ float bl[64];
  __shared__ float W6l[384];
  __shared__ float B6l[8];
  __shared__ __align__(16) float Ht0[64 * 68]; // [c][r]
  __shared__ __align__(16) float Ht1[64 * 68];

  const int e  = blockIdx.x;
  const int s0 = blockIdx.y * 64;
  const int t  = threadIdx.x;
  for (int i = t; i < 384; i += 256) W6l[i] = W6[e * 384 + i];  // BUGFIX r4
  if (t < 6)   B6l[t] = B6[e * 6 + t];

  const float* He = H1a + (size_t)e * (BATCH * 64);
  #pragma unroll
  for (int p = 0; p < 16; ++p) {
    int i = t + p * 256;
    int c = i & 63, r = i >> 6;
    Ht0[c * 68 + r] = fmaxf(He[(size_t)(s0 + r) * 64 + c] + B1[e * 64 + c], 0.f);
  }

  const int tx = t & 15, ty = t >> 4;
  const int c0 = tx * 4, r0 = ty * 4;
  const float* Ws[4] = {W2, W3, W4, W5};
  const float* Bs[4] = {B2, B3, B4, B5};
  float* Hc = Ht0; float* Hn = Ht1;

  for (int L = 0; L < 4; ++L) {
    __syncthreads();
    const float* We = Ws[L] + (size_t)e * 4096;
    for (int i = t; i < 1024; i += 256)
      *(float4*)&Wl[i * 4] = *(const float4*)&We[i * 4];
    if (t < 64) bl[t] = Bs[L][e * 64 + t];
    __syncthreads();

    float acc[4][4] = {};
    #pragma unroll 4
    for (int kk = 0; kk < 64; ++kk) {
      float4 a = *(const float4*)&Hc[kk * 68 + r0];
      float4 bb = *(const float4*)&Wl[kk * 64 + c0];
      float av[4] = {a.x, a.y, a.z, a.w}, bv[4] = {bb.x, bb.y, bb.z, bb.w};
      #pragma unroll
      for (int ii = 0; ii < 4; ++ii)
        #pragma unroll
        for (int j = 0; j < 4; ++j)
          acc[ii][j] += av[ii] * bv[j];
    }
    __syncthreads();
    #pragma unroll
    for (int j = 0; j < 4; ++j) {
      float bias = bl[c0 + j];
      #pragma unroll
      for (int ii = 0; ii < 4; ++ii)
        Hn[(c0 + j) * 68 + r0 + ii] = fmaxf(acc[ii][j] + bias, 0.f);
    }
    float* tmp = Hc; Hc = Hn; Hn = tmp;
  }
  __syncthreads();

  const int r = t & 63, aa = t >> 6;
  float s0v = 0.f, s1v = 0.f;
  for (int k = 0; k < 64; ++k) {
    float h = Hc[k * 68 + r];
    s0v += h * W6l[k * 6 + aa];
    s1v += h * W6l[k * 6 + ((aa < 2) ? aa + 4 : aa)];
  }
  const int s = s0 + r;
  if (rm32[s] == e) {
    out[s * 6 + aa] = s0v + B6l[aa];
    if (aa < 2) out[s * 6 + aa + 4] = s1v + B6l[aa + 4];
  }
}

// ---------------------------------------------------------------------------
extern "C" void kernel_launch(void* const* d_in, const int* in_sizes, int n_in,
                              void* d_out, int out_size, void* d_ws, size_t ws_size,
                              hipStream_t stream) {
  const float* state = (const float*)d_in[0];
  const void*  rm    = d_in[1];
  const float* k1 = (const float*)d_in[2];
  const float* c1 = (const float*)d_in[3];
  const float* k2 = (const float*)d_in[4];
  const float* c2 = (const float*)d_in[5];
  const float* k3 = (const float*)d_in[6];
  const float* c3 = (const float*)d_in[7];
  const float* W1 = (const float*)d_in[8];
  const float* B1 = (const float*)d_in[9];
  const float* W2 = (const float*)d_in[10];
  const float* B2 = (const float*)d_in[11];
  const float* W3 = (const float*)d_in[12];
  const float* B3 = (const float*)d_in[13];
  const float* W4 = (const float*)d_in[14];
  const float* B4 = (const float*)d_in[15];
  const float* W5 = (const float*)d_in[16];
  const float* B5 = (const float*)d_in[17];
  const float* W6 = (const float*)d_in[18];
  const float* B6 = (const float*)d_in[19];

  // workspace layout (~66.7 MB total), all internal buffers fp32
  char* ws = (char*)d_ws;
  float* a3   = (float*)(ws);                  // 2048*3136*4 = 25,690,112
  float* H1a  = (float*)(ws + 25690112);       // 8*2048*64*4 =  4,194,304
  int*   rm32 = (int*)  (ws + 29884416);       // 2048*4      =      8,192
  float* a1c  = (float*)(ws + 29892608);       // 512*12800*4 = 26,214,400
  float* a2c  = (float*)(ws + 56107008);       // 512*5184*4  = 10,616,832
                                               // end: 66,723,840

  hipMemsetAsync(H1a, 0, 8 * BATCH * 64 * sizeof(float), stream);
  rm_norm_kernel<<<1, 1024, 0, stream>>>(rm, rm32);

  for (int b0 = 0; b0 < BATCH; b0 += CH) {
    conv1_kernel<<<dim3(CH, 5), 256, 0, stream>>>(state, k1, c1, a1c, b0);
    conv2_kernel<<<CH, 256, 0, stream>>>(a1c, k2, c2, a2c);
    conv3_kernel<<<CH, 256, 0, stream>>>(a2c, k3, c3, a3, b0);
  }

  gemm1_all_kernel<<<dim3(8, 32, 7), 256, 0, stream>>>(a3, W1, H1a);
  tail_all_kernel<<<dim3(8, 32), 256, 0, stream>>>(H1a, rm32, B1,
                                                   W2, B2, W3, B3, W4, B4,
                                                   W5, B5, W6, B6, (float*)d_out);
}